// Round 14
// baseline (294.921 us; speedup 1.0000x reference)
//
#include <hip/hip_runtime.h>
#include <math.h>
#include <stdint.h>

#define B_      2
#define S_      2048
#define HID_    2048
#define H_      16
#define D_NOPE_ 128
#define D_ROPE_ 64
#define D_V_    128
#define R_      512
#define D_Q_    192
#define NTOK    (B_ * S_)
#define EPS_    1e-6f

typedef __attribute__((ext_vector_type(8))) short bf16x8;
typedef __attribute__((ext_vector_type(4))) float f32x4;

__device__ __forceinline__ short f2bf(float x) {
    union { float f; unsigned u; } un; un.f = x;
    unsigned r = (un.u + 0x7fffu + ((un.u >> 16) & 1u)) >> 16;
    return (short)r;
}
__device__ __forceinline__ float bf2f(short s) {
    union { unsigned u; float f; } un;
    un.u = ((unsigned)(unsigned short)s) << 16;
    return un.f;
}

__device__ __forceinline__ void async_ld16(const short* gsrc, short* ldst) {
    __builtin_amdgcn_global_load_lds(
        (const __attribute__((address_space(1))) void*)gsrc,
        (__attribute__((address_space(3))) void*)ldst, 16, 0, 0);
}

#define BARX() { __builtin_amdgcn_sched_barrier(0); __builtin_amdgcn_s_barrier(); __builtin_amdgcn_sched_barrier(0); }

// ---------------------------------------------------------------------------
// prep: castk (8192 blocks) + 4 transpose_cast regions, one launch.
// ---------------------------------------------------------------------------
__device__ __forceinline__ void tc_body(const float* __restrict__ W,
                                        short* __restrict__ WT,
                                        int K, int Nreal, int bx, int by, int t) {
    __shared__ float T[32][33];
    const int n0 = bx * 32, k0 = by * 32;
    const int r = t >> 3, c4 = (t & 7) * 4;
    float4 v = make_float4(0.f, 0.f, 0.f, 0.f);
    if (n0 < Nreal) v = *(const float4*)&W[(size_t)(k0 + r) * Nreal + n0 + c4];
    T[r][c4 + 0] = v.x; T[r][c4 + 1] = v.y; T[r][c4 + 2] = v.z; T[r][c4 + 3] = v.w;
    __syncthreads();
    const int n = t >> 3, k4 = (t & 7) * 4;
    ushort4 o;
    o.x = (unsigned short)f2bf(T[k4 + 0][n]);
    o.y = (unsigned short)f2bf(T[k4 + 1][n]);
    o.z = (unsigned short)f2bf(T[k4 + 2][n]);
    o.w = (unsigned short)f2bf(T[k4 + 3][n]);
    *(ushort4*)&WT[(size_t)(n0 + n) * K + k0 + k4] = o;
}

__global__ __launch_bounds__(256) void prep(const float* __restrict__ hidden,
                                            short* __restrict__ hid_bf,
                                            const float* __restrict__ Wq,
                                            const float* __restrict__ Wkv_a,
                                            const float* __restrict__ Wkv_b,
                                            const float* __restrict__ Wo,
                                            short* __restrict__ WqkaT,
                                            short* __restrict__ WkbT,
                                            short* __restrict__ WoT) {
    const int bid = blockIdx.x, t = threadIdx.x;
    if (bid < 8192) {
        int i = bid * 256 + t;
        float4 v = ((const float4*)hidden)[i];
        ushort4 o;
        o.x = (unsigned short)f2bf(v.x); o.y = (unsigned short)f2bf(v.y);
        o.z = (unsigned short)f2bf(v.z); o.w = (unsigned short)f2bf(v.w);
        ((ushort4*)hid_bf)[i] = o;
    } else if (bid < 8192 + 6144) {
        int idx = bid - 8192;
        tc_body(Wq, WqkaT, 2048, 3072, idx % 96, idx / 96, t);
    } else if (bid < 8192 + 6144 + 1536) {
        int idx = bid - (8192 + 6144);
        tc_body(Wkv_a, WqkaT + (size_t)3072 * 2048, 2048, 576, idx % 24, idx / 24, t);
    } else if (bid < 8192 + 6144 + 1536 + 2048) {
        int idx = bid - (8192 + 6144 + 1536);
        tc_body(Wkv_b, WkbT, 512, 4096, idx % 128, idx / 128, t);
    } else {
        int idx = bid - (8192 + 6144 + 1536 + 2048);
        tc_body(Wo, WoT, 2048, 2048, idx % 64, idx / 64, t);
    }
}

// ---------------------------------------------------------------------------
// 256x256 8-phase GEMM (T3+T4+T5). 512 threads = 8 waves (2M x 4N).
// ---------------------------------------------------------------------------
template <int QA>
__global__ __launch_bounds__(512) void gemm8(const short* __restrict__ A,
                                             const short* __restrict__ BT,
                                             void* __restrict__ C0,
                                             float* __restrict__ C1,
                                             short* __restrict__ VtOut,
                                             const float* __restrict__ cosT,
                                             const float* __restrict__ sinT,
                                             const int* __restrict__ pid,
                                             int N, int K, int nbx) {
    __shared__ short LB[2][4][8192];   // [buf][A0,A1,B0,B1][256 rows x 32]

    const int tid = threadIdx.x, lane = tid & 63, w = tid >> 6;
    const int c16 = lane & 15, g = lane >> 4;
    const int wr = w >> 2, wc = w & 3;
    const int qph = (g ^ ((c16 >> 1) & 3)) * 8;

    const int nwg = gridDim.x;   // % 8 == 0
    const int swz = (blockIdx.x & 7) * (nwg >> 3) + (blockIdx.x >> 3);
    const int brow = (swz / nbx) * 256, bcol = (swz % nbx) * 256;

    const int o0 = w * 1024 + lane * 16;
    const int o1 = o0 + 8192;
    const int r0 = o0 >> 6, lc0 = ((o0 >> 4) & 3) ^ ((r0 >> 1) & 3);
    const int r1 = o1 >> 6, lc1 = ((o1 >> 4) & 3) ^ ((r1 >> 1) & 3);
    const short* aS0 = A + (size_t)(brow + r0) * K + lc0 * 8;
    const short* aS1 = A + (size_t)(brow + r1) * K + lc1 * 8;
    const short* bS0 = BT + (size_t)(bcol + r0) * K + lc0 * 8;
    const short* bS1 = BT + (size_t)(bcol + r1) * K + lc1 * 8;
    const int d0 = w * 512, d1 = 4096 + w * 512;

    f32x4 zero = {0.f, 0.f, 0.f, 0.f};
    f32x4 acc[8][4];
#pragma unroll
    for (int i = 0; i < 8; ++i)
#pragma unroll
        for (int j = 0; j < 4; ++j) acc[i][j] = zero;

    const int NT = K >> 6;
    async_ld16(aS0,      &LB[0][0][d0]);  async_ld16(aS1,      &LB[0][0][d1]);
    async_ld16(aS0 + 32, &LB[0][1][d0]);  async_ld16(aS1 + 32, &LB[0][1][d1]);
    async_ld16(bS0,      &LB[0][2][d0]);  async_ld16(bS1,      &LB[0][2][d1]);
    async_ld16(bS0 + 32, &LB[0][3][d0]);  async_ld16(bS1 + 32, &LB[0][3][d1]);
    asm volatile("s_waitcnt vmcnt(0)" ::: "memory");
    BARX();

    int cur = 0;
    const int arb = wr * 128, brb = wc * 64;
    for (int kt = 0; kt < NT; ++kt) {
        const bool stg = (kt + 1 < NT);
        const int ko = (kt + 1) * 64;
        short (*CB)[8192] = LB[cur];
        short (*NB)[8192] = LB[cur ^ 1];
        bf16x8 af[4], bf[4];

#pragma unroll
        for (int ni = 0; ni < 4; ++ni)
            bf[ni] = *(const bf16x8*)&CB[2][(brb + ni * 16 + c16) * 32 + qph];
#pragma unroll
        for (int mi = 0; mi < 4; ++mi)
            af[mi] = *(const bf16x8*)&CB[0][(arb + mi * 16 + c16) * 32 + qph];
        if (stg) { async_ld16(aS0 + ko, &NB[0][d0]); async_ld16(aS1 + ko, &NB[0][d1]); }
        BARX();
        __builtin_amdgcn_s_setprio(1);
#pragma unroll
        for (int mi = 0; mi < 4; ++mi)
#pragma unroll
            for (int ni = 0; ni < 4; ++ni)
                acc[mi][ni] = __builtin_amdgcn_mfma_f32_16x16x32_bf16(af[mi], bf[ni], acc[mi][ni], 0, 0, 0);
        __builtin_amdgcn_s_setprio(0);
        BARX();

#pragma unroll
        for (int mi = 0; mi < 4; ++mi)
            af[mi] = *(const bf16x8*)&CB[0][(arb + 64 + mi * 16 + c16) * 32 + qph];
        if (stg) {
            async_ld16(bS0 + ko, &NB[2][d0]); async_ld16(bS1 + ko, &NB[2][d1]);
            asm volatile("s_waitcnt vmcnt(4)" ::: "memory");
        } else {
            asm volatile("s_waitcnt vmcnt(0)" ::: "memory");
        }
        BARX();
        __builtin_amdgcn_s_setprio(1);
#pragma unroll
        for (int mi = 0; mi < 4; ++mi)
#pragma unroll
            for (int ni = 0; ni < 4; ++ni)
                acc[4 + mi][ni] = __builtin_amdgcn_mfma_f32_16x16x32_bf16(af[mi], bf[ni], acc[4 + mi][ni], 0, 0, 0);
        __builtin_amdgcn_s_setprio(0);
        BARX();

#pragma unroll
        for (int ni = 0; ni < 4; ++ni)
            bf[ni] = *(const bf16x8*)&CB[3][(brb + ni * 16 + c16) * 32 + qph];
#pragma unroll
        for (int mi = 0; mi < 4; ++mi)
            af[mi] = *(const bf16x8*)&CB[1][(arb + mi * 16 + c16) * 32 + qph];
        if (stg) { async_ld16(aS0 + ko + 32, &NB[1][d0]); async_ld16(aS1 + ko + 32, &NB[1][d1]); }
        BARX();
        __builtin_amdgcn_s_setprio(1);
#pragma unroll
        for (int mi = 0; mi < 4; ++mi)
#pragma unroll
            for (int ni = 0; ni < 4; ++ni)
                acc[mi][ni] = __builtin_amdgcn_mfma_f32_16x16x32_bf16(af[mi], bf[ni], acc[mi][ni], 0, 0, 0);
        __builtin_amdgcn_s_setprio(0);
        BARX();

#pragma unroll
        for (int mi = 0; mi < 4; ++mi)
            af[mi] = *(const bf16x8*)&CB[1][(arb + 64 + mi * 16 + c16) * 32 + qph];
        if (stg) {
            async_ld16(bS0 + ko + 32, &NB[3][d0]); async_ld16(bS1 + ko + 32, &NB[3][d1]);
            asm volatile("s_waitcnt vmcnt(4)" ::: "memory");
        }
        BARX();
        __builtin_amdgcn_s_setprio(1);
#pragma unroll
        for (int mi = 0; mi < 4; ++mi)
#pragma unroll
            for (int ni = 0; ni < 4; ++ni)
                acc[4 + mi][ni] = __builtin_amdgcn_mfma_f32_16x16x32_bf16(af[mi], bf[ni], acc[4 + mi][ni], 0, 0, 0);
        __builtin_amdgcn_s_setprio(0);
        BARX();

        cur ^= 1;
    }

    if (QA) {
        const int wcol = bcol + wc * 64;
        if (wcol < 3072) {
            short* qb = (short*)C0;
            if ((wcol % 192) == 128) {
#pragma unroll
                for (int mi = 0; mi < 8; ++mi)
#pragma unroll
                    for (int reg = 0; reg < 4; ++reg) {
                        int row = brow + wr * 128 + mi * 16 + 4 * g + reg;
                        int pos = pid[row];
                        float cc1 = cosT[pos * 32 + c16],      ss1 = sinT[pos * 32 + c16];
                        float cc2 = cosT[pos * 32 + 16 + c16], ss2 = sinT[pos * 32 + 16 + c16];
                        float a0 = acc[mi][0][reg], a1 = acc[mi][1][reg];
                        float a2 = acc[mi][2][reg], a3 = acc[mi][3][reg];
                        size_t rb = (size_t)row * 3072 + wcol;
                        qb[rb + c16]      = f2bf(a0 * cc1 - a2 * ss1);
                        qb[rb + 16 + c16] = f2bf(a1 * cc2 - a3 * ss2);
                        qb[rb + 32 + c16] = f2bf(a2 * cc1 + a0 * ss1);
                        qb[rb + 48 + c16] = f2bf(a3 * cc2 + a1 * ss2);
                    }
            } else {
#pragma unroll
                for (int mi = 0; mi < 8; ++mi)
#pragma unroll
                    for (int ni = 0; ni < 4; ++ni)
#pragma unroll
                        for (int reg = 0; reg < 4; ++reg) {
                            int row = brow + wr * 128 + mi * 16 + 4 * g + reg;
                            qb[(size_t)row * 3072 + wcol + ni * 16 + c16] = f2bf(acc[mi][ni][reg]);
                        }
            }
        } else if (wcol < 3712) {
#pragma unroll
            for (int mi = 0; mi < 8; ++mi)
#pragma unroll
                for (int ni = 0; ni < 4; ++ni)
#pragma unroll
                    for (int reg = 0; reg < 4; ++reg) {
                        int row = brow + wr * 128 + mi * 16 + 4 * g + reg;
                        int col = wcol - 3072 + ni * 16 + c16;
                        C1[(size_t)row * 640 + col] = acc[mi][ni][reg];
                    }
        }
    } else {
        short* cc = (short*)C0;
        short* LT = &LB[0][0][0];
        const int wcol = bcol + wc * 64;
        if (wc < 2) {
#pragma unroll
            for (int mi = 0; mi < 8; ++mi)
#pragma unroll
                for (int ni = 0; ni < 4; ++ni)
#pragma unroll
                    for (int reg = 0; reg < 4; ++reg) {
                        int row = brow + wr * 128 + mi * 16 + 4 * g + reg;
                        cc[(size_t)row * N + wcol + ni * 16 + c16] = f2bf(acc[mi][ni][reg]);
                    }
        } else {
#pragma unroll
            for (int mi = 0; mi < 8; ++mi)
#pragma unroll
                for (int ni = 0; ni < 4; ++ni)
#pragma unroll
                    for (int reg = 0; reg < 4; ++reg) {
                        int d = wc * 64 - 128 + ni * 16 + c16;
                        int s = wr * 128 + mi * 16 + 4 * g + reg;
                        LT[d * 256 + (s ^ ((d & 15) << 3))] = f2bf(acc[mi][ni][reg]);
                    }
        }
        __syncthreads();
        const int bb = brow >> 11, hh = bcol >> 8, sbase = brow & 2047;
#pragma unroll
        for (int j = 0; j < 8; ++j) {
            int d = j * 16 + (tid >> 5);
            int s0 = (tid & 31) * 8;
            bf16x8 v = *(const bf16x8*)&LT[d * 256 + (s0 ^ ((d & 15) << 3))];
            *(bf16x8*)&VtOut[((size_t)((bb * 16 + hh) * 128 + d)) * 2048 + sbase + s0] = v;
        }
    }
}

// ---------------------------------------------------------------------------
// 128x256 counted-vmcnt GEMM for gemm_out.
// ---------------------------------------------------------------------------
__global__ __launch_bounds__(512) void gemm8n(const short* __restrict__ A,
                                              const short* __restrict__ BT,
                                              float* __restrict__ C,
                                              int N, int K, int nbx) {
    __shared__ short LA[2][2][4096];
    __shared__ short LBt[2][2][8192];

    const int tid = threadIdx.x, lane = tid & 63, w = tid >> 6;
    const int c16 = lane & 15, g = lane >> 4;
    const int wr = w >> 2, wc = w & 3;
    const int qph = (g ^ ((c16 >> 1) & 3)) * 8;

    const int nwg = gridDim.x;
    const int swz = (blockIdx.x & 7) * (nwg >> 3) + (blockIdx.x >> 3);
    const int brow = (swz / nbx) * 128, bcol = (swz % nbx) * 256;

    const int oA = tid * 16;
    const int rA = oA >> 6, lcA = ((oA >> 4) & 3) ^ ((rA >> 1) & 3);
    const short* aS = A + (size_t)(brow + rA) * K + lcA * 8;
    const int dA = oA >> 1;

    const int o0 = w * 1024 + lane * 16, o1 = o0 + 8192;
    const int r0 = o0 >> 6, lc0 = ((o0 >> 4) & 3) ^ ((r0 >> 1) & 3);
    const int r1 = o1 >> 6, lc1 = ((o1 >> 4) & 3) ^ ((r1 >> 1) & 3);
    const short* bS0 = BT + (size_t)(bcol + r0) * K + lc0 * 8;
    const short* bS1 = BT + (size_t)(bcol + r1) * K + lc1 * 8;
    const int d0 = o0 >> 1, d1 = o1 >> 1;

    f32x4 zero = {0.f, 0.f, 0.f, 0.f};
    f32x4 acc[4][4];
#pragma unroll
    for (int i = 0; i < 4; ++i)
#pragma unroll
        for (int j = 0; j < 4; ++j) acc[i][j] = zero;

    const int NT = K >> 6;
    async_ld16(aS,      &LA[0][0][dA]);
    async_ld16(aS + 32, &LA[0][1][dA]);
    async_ld16(bS0,      &LBt[0][0][d0]); async_ld16(bS1,      &LBt[0][0][d1]);
    async_ld16(bS0 + 32, &LBt[0][1][d0]); async_ld16(bS1 + 32, &LBt[0][1][d1]);
    asm volatile("s_waitcnt vmcnt(0)" ::: "memory");
    BARX();

    int cur = 0;
    const int arb = wr * 64, brb = wc * 64;
    for (int kt = 0; kt < NT; ++kt) {
        const bool stg = (kt + 1 < NT);
        const int ko = (kt + 1) * 64;
        bf16x8 af[4], bf[4];

#pragma unroll
        for (int mi = 0; mi < 4; ++mi)
            af[mi] = *(const bf16x8*)&LA[cur][0][(arb + mi * 16 + c16) * 32 + qph];
#pragma unroll
        for (int ni = 0; ni < 4; ++ni)
            bf[ni] = *(const bf16x8*)&LBt[cur][0][(brb + ni * 16 + c16) * 32 + qph];
        if (stg) {
            async_ld16(aS + ko, &LA[cur ^ 1][0][dA]);
            async_ld16(bS0 + ko, &LBt[cur ^ 1][0][d0]);
            async_ld16(bS1 + ko, &LBt[cur ^ 1][0][d1]);
            asm volatile("s_waitcnt vmcnt(3)" ::: "memory");
        } else {
            asm volatile("s_waitcnt vmcnt(0)" ::: "memory");
        }
        BARX();
        __builtin_amdgcn_s_setprio(1);
#pragma unroll
        for (int mi = 0; mi < 4; ++mi)
#pragma unroll
            for (int ni = 0; ni < 4; ++ni)
                acc[mi][ni] = __builtin_amdgcn_mfma_f32_16x16x32_bf16(af[mi], bf[ni], acc[mi][ni], 0, 0, 0);
        __builtin_amdgcn_s_setprio(0);
        BARX();

#pragma unroll
        for (int mi = 0; mi < 4; ++mi)
            af[mi] = *(const bf16x8*)&LA[cur][1][(arb + mi * 16 + c16) * 32 + qph];
#pragma unroll
        for (int ni = 0; ni < 4; ++ni)
            bf[ni] = *(const bf16x8*)&LBt[cur][1][(brb + ni * 16 + c16) * 32 + qph];
        if (stg) {
            async_ld16(aS + ko + 32, &LA[cur ^ 1][1][dA]);
            async_ld16(bS0 + ko + 32, &LBt[cur ^ 1][1][d0]);
            async_ld16(bS1 + ko + 32, &LBt[cur ^ 1][1][d1]);
            asm volatile("s_waitcnt vmcnt(3)" ::: "memory");
        }
        BARX();
        __builtin_amdgcn_s_setprio(1);
#pragma unroll
        for (int mi = 0; mi < 4; ++mi)
#pragma unroll
            for (int ni = 0; ni < 4; ++ni)
                acc[mi][ni] = __builtin_amdgcn_mfma_f32_16x16x32_bf16(af[mi], bf[ni], acc[mi][ni], 0, 0, 0);
        __builtin_amdgcn_s_setprio(0);
        BARX();

        cur ^= 1;
    }

#pragma unroll
    for (int mi = 0; mi < 4; ++mi)
#pragma unroll
        for (int ni = 0; ni < 4; ++ni)
#pragma unroll
            for (int reg = 0; reg < 4; ++reg) {
                int row = brow + wr * 64 + mi * 16 + 4 * g + reg;
                int col = bcol + wc * 64 + ni * 16 + c16;
                C[(size_t)row * N + col] = acc[mi][ni][reg];
            }
}

// ---------------------------------------------------------------------------
// LayerNorm(512) + RoPE(k_pe). ckv stride 640. Outputs bf16.
// ---------------------------------------------------------------------------
__global__ __launch_bounds__(256) void ln_rope(const float* __restrict__ ckv,
                                               const float* __restrict__ gam,
                                               const float* __restrict__ bet,
                                               const float* __restrict__ cosT,
                                               const float* __restrict__ sinT,
                                               const int* __restrict__ pid,
                                               short* __restrict__ kvcn,
                                               short* __restrict__ kpe) {
    const int tok = blockIdx.x, tid = threadIdx.x;
    const float* x = ckv + (size_t)tok * 640;
    float v0 = x[tid], v1 = x[tid + 256];
    float s = v0 + v1, sq = v0 * v0 + v1 * v1;
#pragma unroll
    for (int m = 1; m < 64; m <<= 1) { s += __shfl_xor(s, m); sq += __shfl_xor(sq, m); }
    __shared__ float ws[8];
    int wid = tid >> 6, lane = tid & 63;
    if (lane == 0) { ws[wid] = s; ws[4 + wid] = sq; }
    __syncthreads();
    s = ws[0] + ws[1] + ws[2] + ws[3];
    sq = ws[4] + ws[5] + ws[6] + ws[7];
    float mean = s * (1.f / 512.f);
    float var = sq * (1.f / 512.f) - mean * mean;
    float rstd = rsqrtf(var + EPS_);
    kvcn[(size_t)tok * 512 + tid]       = f2bf((v0 - mean) * rstd * gam[tid] + bet[tid]);
    kvcn[(size_t)tok * 512 + tid + 256] = f2bf((v1 - mean) * rstd * gam[tid + 256] + bet[tid + 256]);
    if (tid < 32) {
        int pos = pid[tok];
        float c = cosT[pos * 32 + tid], sn = sinT[pos * 32 + tid];
        float x1 = x[512 + tid], x2 = x[512 + 32 + tid];
        kpe[(size_t)tok * 64 + tid]      = f2bf(x1 * c - x2 * sn);
        kpe[(size_t)tok * 64 + 32 + tid] = f2bf(x2 * c + x1 * sn);
    }
}

// ---------------------------------------------------------------------------
// MFMA flash attention. SINGLE-BUFFERED K/V (LDS 40K -> 3 blocks/CU) with
// split staged-overlap: STAGE_K(kt+1) after the QK-consume barrier (lands
// under softmax+PV), STAGE_V(kt+1) after the PV-consume barrier (lands under
// next QK). Swapped QK^T softmax (R13). 1024 blocks, one q-tile each,
// long-first, XCD-pinned.
// ---------------------------------------------------------------------------
__global__ __launch_bounds__(256, 3) void flash_mfma(const short* __restrict__ qb,
                                                     const short* __restrict__ kvb,
                                                     const short* __restrict__ kpe,
                                                     const short* __restrict__ Vt,
                                                     short* __restrict__ attno) {
    __shared__ short Ks[64 * 128];
    __shared__ short Vs[128 * 64];
    __shared__ short P[4][16][72];

    const int flat = blockIdx.x;              // 0..1023
    const int xcd = flat & 7, idx = flat >> 3;
    const int bh = xcd + 8 * (idx >> 5);      // all q-tiles of a bh on one XCD
    const int qt = 31 - (idx & 31);           // long blocks first
    const int b = bh >> 4, h = bh & 15;
    const int q0 = qt * 64;

    const int tid = threadIdx.x, lane = tid & 63, w = tid >> 6;
    const int c16 = lane & 15, g = lane >> 4, g8 = g * 8;
    const float SC2 = 0.10412063f;   // 1/sqrt(192) * log2(e)

    const int o = w * 1024 + lane * 16;
    const int rK = o >> 8, ccK = ((o >> 4) & 15) ^ (rK & 7);
    const int rV = o >> 7, ccV = ((o >> 4) & 7) ^ (rV & 7);
    const short* kRun = kvb + ((size_t)((b * 2048 + rK) * 16 + h)) * 256 + ccK * 8;
    const short* vRun = Vt + ((size_t)((b * 16 + h) * 128 + rV)) * 2048 + ccV * 8;
    const short* peRun = kpe + (size_t)(b * 2048 + c16) * 64 + g8;

    const int qrow = q0 + w * 16;
    const size_t qbase = ((size_t)(b * 2048 + qrow + c16) * 16 + h) * 192 + g8;
    bf16x8 qf[6];
#pragma unroll
    for (int ks = 0; ks < 6; ++ks) qf[ks] = *(const bf16x8*)(qb + qbase + 32 * ks);

    f32x4 zero = {0.f, 0.f, 0.f, 0.f};
    f32x4 acc[8];
#pragma unroll
    for (int i = 0; i < 8; ++i) acc[i] = zero;
    float mreg = -INFINITY;   // running max for q-row c16 (lane-local)
    float lreg = 0.f;         // per-lane partial row sum

#define STAGE_K()                                                                   \
    {                                                                               \
        _Pragma("unroll")                                                           \
        for (int rnd = 0; rnd < 4; ++rnd)                                           \
            async_ld16(kRun + (size_t)rnd * 65536,                                  \
                       &Ks[(rnd * 4096 + w * 1024) >> 1]);                          \
        kRun += 64 * 4096;                                                          \
    }
#define STAGE_V()                                                                   \
    {                                                                               \
        _Pragma("unroll")                                                           \
        for (int rnd = 0; rnd < 4; ++rnd)                                           \
            async_ld16(vRun + (size_t)rnd * 65536,                                  \
                       &Vs[(rnd * 4096 + w * 1024) >> 1]);                          \
        vRun += 64;                                                                 \
    }

    const int nt = qt + 1;
    STAGE_K();
    STAGE_V();
    __syncthreads();   // drains own vmcnt -> tile 0 resident for all waves

    for (int kt = 0; kt < nt; ++kt) {
        const bool stg = (kt + 1 < nt);

        f32x4 sc[4];
#pragma unroll
        for (int i = 0; i < 4; ++i) sc[i] = zero;

        // QK^T swapped: A = K fragment, B = Q fragment -> S[kv][q=c16]
        __builtin_amdgcn_s_setprio(1);
#pragma unroll
        for (int ks = 0; ks < 4; ++ks)
#pragma unroll
            for (int nb = 0; nb < 4; ++nb) {
                int row = nb * 16 + c16;
                bf16x8 kf = *(const bf16x8*)&Ks[row * 128 + (((g + 4 * ks) ^ (row & 7)) << 3)];
                sc[nb] = __builtin_amdgcn_mfma_f32_16x16x32_bf16(kf, qf[ks], sc[nb], 0, 0, 0);
            }
#pragma unroll
        for (int ks = 0; ks < 2; ++ks)
#pragma unroll
            for (int nb = 0; nb < 4; ++nb) {
                bf16x8 kf = *(const bf16x8*)(peRun + (size_t)nb * 16 * 64 + ks * 32);
                sc[nb] = __builtin_amdgcn_mfma_f32_16x16x32_bf16(kf, qf[4 + ks], sc[nb], 0, 0, 0);
            }
        __builtin_amdgcn_s_setprio(0);
        peRun += 64 * 64;

        __syncthreads();           // all waves done reading Ks
        if (stg) STAGE_K();        // overwrite Ks; lands under softmax+PV

        // causal mask (last tile): kv_rel = 16nb+4g+reg > w*16 + c16
        if (kt == nt - 1) {
#pragma unroll
            for (int nb = 0; nb < 4; ++nb)
#pragma unroll
                for (int reg = 0; reg < 4; ++reg)
                    if (nb * 16 + 4 * g + reg > w * 16 + c16) sc[nb][reg] = -INFINITY;
        }

        // row max: local tree (16 values) + 2 shuffle rounds
        float m01 = fmaxf(fmaxf(sc[0][0], sc[0][1]), fmaxf(sc[0][2], sc[0][3]));
        float m23 = fmaxf(fmaxf(sc[1][0], sc[1][1]), fmaxf(sc[1][2], sc[1][3]));
        float m45 = fmaxf(fmaxf(sc[2][0], sc[2][1]), fmaxf(sc[2][2], sc[2][3]));
        float m67 = fmaxf(fmaxf(sc[3][0], sc[3][1]), fmaxf(sc[3][2], sc[3][3]));
        float rmax = fmaxf(fmaxf(m01, m23), fmaxf(m45, m67));
        rmax = fmaxf(rmax, __shfl_xor(rmax, 16));
        rmax = fmaxf(rmax, __shfl_xor(rmax, 32));

        // defer-rescale (T13, THR=8 in log2 domain)
        if (__any(rmax * SC2 - mreg > 8.f)) {
            float mnew = fmaxf(mreg, rmax * SC2);
            float alpha = exp2f(mreg - mnew);
            mreg = mnew;
            lreg *= alpha;
            float ar[4];
#pragma unroll
            for (int reg = 0; reg < 4; ++reg) ar[reg] = __shfl(alpha, 4 * g + reg);
#pragma unroll
            for (int nb = 0; nb < 8; ++nb)
#pragma unroll
                for (int reg = 0; reg < 4; ++reg) acc[nb][reg] *= ar[reg];
        }

        // p = 2^(s*SC2 - m); per-lane partial sum; write P[q=c16][kv]
#pragma unroll
        for (int nb = 0; nb < 4; ++nb) {
            float p0 = exp2f(fmaf(sc[nb][0], SC2, -mreg));
            float p1 = exp2f(fmaf(sc[nb][1], SC2, -mreg));
            float p2 = exp2f(fmaf(sc[nb][2], SC2, -mreg));
            float p3 = exp2f(fmaf(sc[nb][3], SC2, -mreg));
            lreg += (p0 + p1) + (p2 + p3);
            short* pr = &P[w][c16][nb * 16 + 4 * g];
            pr[0] = f2bf(p0); pr[1] = f2bf(p1); pr[2] = f2bf(p2); pr[3] = f2bf(p3);
        }

        // PV from LDS V
        __builtin_amdgcn_s_setprio(1);
#pragma unroll
        for (int ks = 0; ks < 2; ++ks) {
            bf16x8 pf = *(const bf16x8*)&P[w][c16][ks * 32 + g8];
#pragma unroll
            for (int nb = 0; nb < 8; ++nb) {
                int row = nb * 16 + c16;
                bf16x8 vf = *(const bf16x8*)&Vs[row * 64 + (((g + 4 * ks) ^ (row & 7)) << 3)];
                acc[nb] = __builtin_amdgcn_mfma_f32_16x16x32_bf16(pf, vf, acc[nb], 0, 0, 0);
            }
        }
        __builtin_amdgcn_s_setprio(0);

        __syncthreads();           // all waves done reading Vs; own K-stage drained
        if (stg) STAGE_V();        // overwrite Vs; lands under next QK
    }
#undef STAGE_K
#undef STAGE_V

    // epilogue: finish deferred row-sum (2 rounds), transpose to PV domain
    lreg += __shfl_xor(lreg, 16);
    lreg += __shfl_xor(lreg, 32);
    float linv[4];
#pragma unroll
    for (int reg = 0; reg < 4; ++reg) linv[reg] = 1.f / __shfl(lreg, 4 * g + reg);
#pragma unroll
    for (int nb = 0; nb < 8; ++nb)
#pragma unroll
        for (int reg = 0; reg < 4; ++reg)
            attno[((size_t)(b * 2048 + qrow + 4 * g + reg) * 16 + h) * 128 + nb * 16 + c16] =
                f2bf(acc[nb][reg] * linv[reg]);
}

// ---------------------------------------------------------------------------
extern "C" void kernel_launch(void* const* d_in, const int* in_sizes, int n_in,
                              void* d_out, int out_size, void* d_ws, size_t ws_size,
                              hipStream_t stream) {
    const float* hidden = (const float*)d_in[0];
    const float* cosT   = (const float*)d_in[1];
    const float* sinT   = (const float*)d_in[2];
    const int*   pid    = (const int*)d_in[3];
    const float* Wq     = (const float*)d_in[4];
    const float* Wkv_a  = (const float*)d_in[5];
    const float* ln_g   = (const float*)d_in[6];
    const float* ln_b   = (const float*)d_in[7];
    const float* Wkv_b  = (const float*)d_in[8];
    const float* Wo     = (const float*)d_in[9];
    float* out = (float*)d_out;

    char* p = (char*)d_ws;
    short* hid_bf = (short*)p;               p += (size_t)NTOK * 2048 * 2;
    short* WqkaT  = (short*)p;               p += (size_t)3840 * 2048 * 2;
    short* WkbT   = (short*)p;               p += (size_t)4096 * 512 * 2;
    short* WoT    = (short*)p;               p += (size_t)2048 * 2048 * 2;
    char*  big    = p;                       p += (size_t)NTOK * 3072 * 4;
    short* qbuf   = (short*)p;               p += (size_t)NTOK * 3072 * 2;
    short* kvcn   = (short*)p;               p += (size_t)NTOK * 512 * 2;
    short* kpe    = (short*)p;               p += (size_t)NTOK * 64 * 2;
    short* kvb    = (short*)p;               p += (size_t)NTOK * 4096 * 2;

    float* ckv   = (float*)big;
    short* Vt    = (short*)(big + (size_t)NTOK * 640 * 4);
    short* attno = (short*)(big + (size_t)NTOK * 640 * 4 + (size_t)2 * 16 * 128 * 2048 * 2);

    prep<<<22016, 256, 0, stream>>>(hidden, hid_bf, Wq, Wkv_a, Wkv_b, Wo, WqkaT, WkbT, WoT);
    gemm8<1><<<240, 512, 0, stream>>>(hid_bf, WqkaT, qbuf, ckv, nullptr,
                                      cosT, sinT, pid, 3840, 2048, 15);
    ln_rope<<<NTOK, 256, 0, stream>>>(ckv, ln_g, ln_b, cosT, sinT, pid, kvcn, kpe);
    gemm8<0><<<256, 512, 0, stream>>>(kvcn, WkbT, kvb, nullptr, Vt,
                                      nullptr, nullptr, nullptr, 4096, 512, 16);
    flash_mfma<<<1024, 256, 0, stream>>>(qbuf, kvb, kpe, Vt, attno);
    gemm8n<<<256, 512, 0, stream>>>(attno, WoT, out, 2048, 2048, 8);
}

// Round 15
// 274.387 us; speedup vs baseline: 1.0748x; 1.0748x over previous
//
#include <hip/hip_runtime.h>
#include <math.h>
#include <stdint.h>

#define B_      2
#define S_      2048
#define HID_    2048
#define H_      16
#define D_NOPE_ 128
#define D_ROPE_ 64
#define D_V_    128
#define R_      512
#define D_Q_    192
#define NTOK    (B_ * S_)
#define EPS_    1e-6f

typedef __attribute__((ext_vector_type(8))) short bf16x8;
typedef __attribute__((ext_vector_type(4))) float f32x4;

__device__ __forceinline__ short f2bf(float x) {
    union { float f; unsigned u; } un; un.f = x;
    unsigned r = (un.u + 0x7fffu + ((un.u >> 16) & 1u)) >> 16;
    return (short)r;
}
__device__ __forceinline__ float bf2f(short s) {
    union { unsigned u; float f; } un;
    un.u = ((unsigned)(unsigned short)s) << 16;
    return un.f;
}

__device__ __forceinline__ void async_ld16(const short* gsrc, short* ldst) {
    __builtin_amdgcn_global_load_lds(
        (const __attribute__((address_space(1))) void*)gsrc,
        (__attribute__((address_space(3))) void*)ldst, 16, 0, 0);
}

#define BARX() { __builtin_amdgcn_sched_barrier(0); __builtin_amdgcn_s_barrier(); __builtin_amdgcn_sched_barrier(0); }

// ---------------------------------------------------------------------------
// prep: castk (8192 blocks) + 4 transpose_cast regions, one launch.
// ---------------------------------------------------------------------------
__device__ __forceinline__ void tc_body(const float* __restrict__ W,
                                        short* __restrict__ WT,
                                        int K, int Nreal, int bx, int by, int t) {
    __shared__ float T[32][33];
    const int n0 = bx * 32, k0 = by * 32;
    const int r = t >> 3, c4 = (t & 7) * 4;
    float4 v = make_float4(0.f, 0.f, 0.f, 0.f);
    if (n0 < Nreal) v = *(const float4*)&W[(size_t)(k0 + r) * Nreal + n0 + c4];
    T[r][c4 + 0] = v.x; T[r][c4 + 1] = v.y; T[r][c4 + 2] = v.z; T[r][c4 + 3] = v.w;
    __syncthreads();
    const int n = t >> 3, k4 = (t & 7) * 4;
    ushort4 o;
    o.x = (unsigned short)f2bf(T[k4 + 0][n]);
    o.y = (unsigned short)f2bf(T[k4 + 1][n]);
    o.z = (unsigned short)f2bf(T[k4 + 2][n]);
    o.w = (unsigned short)f2bf(T[k4 + 3][n]);
    *(ushort4*)&WT[(size_t)(n0 + n) * K + k0 + k4] = o;
}

__global__ __launch_bounds__(256) void prep(const float* __restrict__ hidden,
                                            short* __restrict__ hid_bf,
                                            const float* __restrict__ Wq,
                                            const float* __restrict__ Wkv_a,
                                            const float* __restrict__ Wkv_b,
                                            const float* __restrict__ Wo,
                                            short* __restrict__ WqkaT,
                                            short* __restrict__ WkbT,
                                            short* __restrict__ WoT) {
    const int bid = blockIdx.x, t = threadIdx.x;
    if (bid < 8192) {
        int i = bid * 256 + t;
        float4 v = ((const float4*)hidden)[i];
        ushort4 o;
        o.x = (unsigned short)f2bf(v.x); o.y = (unsigned short)f2bf(v.y);
        o.z = (unsigned short)f2bf(v.z); o.w = (unsigned short)f2bf(v.w);
        ((ushort4*)hid_bf)[i] = o;
    } else if (bid < 8192 + 6144) {
        int idx = bid - 8192;
        tc_body(Wq, WqkaT, 2048, 3072, idx % 96, idx / 96, t);
    } else if (bid < 8192 + 6144 + 1536) {
        int idx = bid - (8192 + 6144);
        tc_body(Wkv_a, WqkaT + (size_t)3072 * 2048, 2048, 576, idx % 24, idx / 24, t);
    } else if (bid < 8192 + 6144 + 1536 + 2048) {
        int idx = bid - (8192 + 6144 + 1536);
        tc_body(Wkv_b, WkbT, 512, 4096, idx % 128, idx / 128, t);
    } else {
        int idx = bid - (8192 + 6144 + 1536 + 2048);
        tc_body(Wo, WoT, 2048, 2048, idx % 64, idx / 64, t);
    }
}

// ---------------------------------------------------------------------------
// 256x256 8-phase GEMM (T3+T4+T5). 512 threads = 8 waves (2M x 4N).
// ---------------------------------------------------------------------------
template <int QA>
__global__ __launch_bounds__(512) void gemm8(const short* __restrict__ A,
                                             const short* __restrict__ BT,
                                             void* __restrict__ C0,
                                             float* __restrict__ C1,
                                             short* __restrict__ VtOut,
                                             const float* __restrict__ cosT,
                                             const float* __restrict__ sinT,
                                             const int* __restrict__ pid,
                                             int N, int K, int nbx) {
    __shared__ short LB[2][4][8192];   // [buf][A0,A1,B0,B1][256 rows x 32]

    const int tid = threadIdx.x, lane = tid & 63, w = tid >> 6;
    const int c16 = lane & 15, g = lane >> 4;
    const int wr = w >> 2, wc = w & 3;
    const int qph = (g ^ ((c16 >> 1) & 3)) * 8;

    const int nwg = gridDim.x;   // % 8 == 0
    const int swz = (blockIdx.x & 7) * (nwg >> 3) + (blockIdx.x >> 3);
    const int brow = (swz / nbx) * 256, bcol = (swz % nbx) * 256;

    const int o0 = w * 1024 + lane * 16;
    const int o1 = o0 + 8192;
    const int r0 = o0 >> 6, lc0 = ((o0 >> 4) & 3) ^ ((r0 >> 1) & 3);
    const int r1 = o1 >> 6, lc1 = ((o1 >> 4) & 3) ^ ((r1 >> 1) & 3);
    const short* aS0 = A + (size_t)(brow + r0) * K + lc0 * 8;
    const short* aS1 = A + (size_t)(brow + r1) * K + lc1 * 8;
    const short* bS0 = BT + (size_t)(bcol + r0) * K + lc0 * 8;
    const short* bS1 = BT + (size_t)(bcol + r1) * K + lc1 * 8;
    const int d0 = w * 512, d1 = 4096 + w * 512;

    f32x4 zero = {0.f, 0.f, 0.f, 0.f};
    f32x4 acc[8][4];
#pragma unroll
    for (int i = 0; i < 8; ++i)
#pragma unroll
        for (int j = 0; j < 4; ++j) acc[i][j] = zero;

    const int NT = K >> 6;
    async_ld16(aS0,      &LB[0][0][d0]);  async_ld16(aS1,      &LB[0][0][d1]);
    async_ld16(aS0 + 32, &LB[0][1][d0]);  async_ld16(aS1 + 32, &LB[0][1][d1]);
    async_ld16(bS0,      &LB[0][2][d0]);  async_ld16(bS1,      &LB[0][2][d1]);
    async_ld16(bS0 + 32, &LB[0][3][d0]);  async_ld16(bS1 + 32, &LB[0][3][d1]);
    asm volatile("s_waitcnt vmcnt(0)" ::: "memory");
    BARX();

    int cur = 0;
    const int arb = wr * 128, brb = wc * 64;
    for (int kt = 0; kt < NT; ++kt) {
        const bool stg = (kt + 1 < NT);
        const int ko = (kt + 1) * 64;
        short (*CB)[8192] = LB[cur];
        short (*NB)[8192] = LB[cur ^ 1];
        bf16x8 af[4], bf[4];

#pragma unroll
        for (int ni = 0; ni < 4; ++ni)
            bf[ni] = *(const bf16x8*)&CB[2][(brb + ni * 16 + c16) * 32 + qph];
#pragma unroll
        for (int mi = 0; mi < 4; ++mi)
            af[mi] = *(const bf16x8*)&CB[0][(arb + mi * 16 + c16) * 32 + qph];
        if (stg) { async_ld16(aS0 + ko, &NB[0][d0]); async_ld16(aS1 + ko, &NB[0][d1]); }
        BARX();
        __builtin_amdgcn_s_setprio(1);
#pragma unroll
        for (int mi = 0; mi < 4; ++mi)
#pragma unroll
            for (int ni = 0; ni < 4; ++ni)
                acc[mi][ni] = __builtin_amdgcn_mfma_f32_16x16x32_bf16(af[mi], bf[ni], acc[mi][ni], 0, 0, 0);
        __builtin_amdgcn_s_setprio(0);
        BARX();

#pragma unroll
        for (int mi = 0; mi < 4; ++mi)
            af[mi] = *(const bf16x8*)&CB[0][(arb + 64 + mi * 16 + c16) * 32 + qph];
        if (stg) {
            async_ld16(bS0 + ko, &NB[2][d0]); async_ld16(bS1 + ko, &NB[2][d1]);
            asm volatile("s_waitcnt vmcnt(4)" ::: "memory");
        } else {
            asm volatile("s_waitcnt vmcnt(0)" ::: "memory");
        }
        BARX();
        __builtin_amdgcn_s_setprio(1);
#pragma unroll
        for (int mi = 0; mi < 4; ++mi)
#pragma unroll
            for (int ni = 0; ni < 4; ++ni)
                acc[4 + mi][ni] = __builtin_amdgcn_mfma_f32_16x16x32_bf16(af[mi], bf[ni], acc[4 + mi][ni], 0, 0, 0);
        __builtin_amdgcn_s_setprio(0);
        BARX();

#pragma unroll
        for (int ni = 0; ni < 4; ++ni)
            bf[ni] = *(const bf16x8*)&CB[3][(brb + ni * 16 + c16) * 32 + qph];
#pragma unroll
        for (int mi = 0; mi < 4; ++mi)
            af[mi] = *(const bf16x8*)&CB[1][(arb + mi * 16 + c16) * 32 + qph];
        if (stg) { async_ld16(aS0 + ko + 32, &NB[1][d0]); async_ld16(aS1 + ko + 32, &NB[1][d1]); }
        BARX();
        __builtin_amdgcn_s_setprio(1);
#pragma unroll
        for (int mi = 0; mi < 4; ++mi)
#pragma unroll
            for (int ni = 0; ni < 4; ++ni)
                acc[mi][ni] = __builtin_amdgcn_mfma_f32_16x16x32_bf16(af[mi], bf[ni], acc[mi][ni], 0, 0, 0);
        __builtin_amdgcn_s_setprio(0);
        BARX();

#pragma unroll
        for (int mi = 0; mi < 4; ++mi)
            af[mi] = *(const bf16x8*)&CB[1][(arb + 64 + mi * 16 + c16) * 32 + qph];
        if (stg) {
            async_ld16(bS0 + ko + 32, &NB[3][d0]); async_ld16(bS1 + ko + 32, &NB[3][d1]);
            asm volatile("s_waitcnt vmcnt(4)" ::: "memory");
        }
        BARX();
        __builtin_amdgcn_s_setprio(1);
#pragma unroll
        for (int mi = 0; mi < 4; ++mi)
#pragma unroll
            for (int ni = 0; ni < 4; ++ni)
                acc[4 + mi][ni] = __builtin_amdgcn_mfma_f32_16x16x32_bf16(af[mi], bf[ni], acc[4 + mi][ni], 0, 0, 0);
        __builtin_amdgcn_s_setprio(0);
        BARX();

        cur ^= 1;
    }

    if (QA) {
        const int wcol = bcol + wc * 64;
        if (wcol < 3072) {
            short* qb = (short*)C0;
            if ((wcol % 192) == 128) {
#pragma unroll
                for (int mi = 0; mi < 8; ++mi)
#pragma unroll
                    for (int reg = 0; reg < 4; ++reg) {
                        int row = brow + wr * 128 + mi * 16 + 4 * g + reg;
                        int pos = pid[row];
                        float cc1 = cosT[pos * 32 + c16],      ss1 = sinT[pos * 32 + c16];
                        float cc2 = cosT[pos * 32 + 16 + c16], ss2 = sinT[pos * 32 + 16 + c16];
                        float a0 = acc[mi][0][reg], a1 = acc[mi][1][reg];
                        float a2 = acc[mi][2][reg], a3 = acc[mi][3][reg];
                        size_t rb = (size_t)row * 3072 + wcol;
                        qb[rb + c16]      = f2bf(a0 * cc1 - a2 * ss1);
                        qb[rb + 16 + c16] = f2bf(a1 * cc2 - a3 * ss2);
                        qb[rb + 32 + c16] = f2bf(a2 * cc1 + a0 * ss1);
                        qb[rb + 48 + c16] = f2bf(a3 * cc2 + a1 * ss2);
                    }
            } else {
#pragma unroll
                for (int mi = 0; mi < 8; ++mi)
#pragma unroll
                    for (int ni = 0; ni < 4; ++ni)
#pragma unroll
                        for (int reg = 0; reg < 4; ++reg) {
                            int row = brow + wr * 128 + mi * 16 + 4 * g + reg;
                            qb[(size_t)row * 3072 + wcol + ni * 16 + c16] = f2bf(acc[mi][ni][reg]);
                        }
            }
        } else if (wcol < 3712) {
#pragma unroll
            for (int mi = 0; mi < 8; ++mi)
#pragma unroll
                for (int ni = 0; ni < 4; ++ni)
#pragma unroll
                    for (int reg = 0; reg < 4; ++reg) {
                        int row = brow + wr * 128 + mi * 16 + 4 * g + reg;
                        int col = wcol - 3072 + ni * 16 + c16;
                        C1[(size_t)row * 640 + col] = acc[mi][ni][reg];
                    }
        }
    } else {
        short* cc = (short*)C0;
        short* LT = &LB[0][0][0];
        const int wcol = bcol + wc * 64;
        if (wc < 2) {
#pragma unroll
            for (int mi = 0; mi < 8; ++mi)
#pragma unroll
                for (int ni = 0; ni < 4; ++ni)
#pragma unroll
                    for (int reg = 0; reg < 4; ++reg) {
                        int row = brow + wr * 128 + mi * 16 + 4 * g + reg;
                        cc[(size_t)row * N + wcol + ni * 16 + c16] = f2bf(acc[mi][ni][reg]);
                    }
        } else {
#pragma unroll
            for (int mi = 0; mi < 8; ++mi)
#pragma unroll
                for (int ni = 0; ni < 4; ++ni)
#pragma unroll
                    for (int reg = 0; reg < 4; ++reg) {
                        int d = wc * 64 - 128 + ni * 16 + c16;
                        int s = wr * 128 + mi * 16 + 4 * g + reg;
                        LT[d * 256 + (s ^ ((d & 15) << 3))] = f2bf(acc[mi][ni][reg]);
                    }
        }
        __syncthreads();
        const int bb = brow >> 11, hh = bcol >> 8, sbase = brow & 2047;
#pragma unroll
        for (int j = 0; j < 8; ++j) {
            int d = j * 16 + (tid >> 5);
            int s0 = (tid & 31) * 8;
            bf16x8 v = *(const bf16x8*)&LT[d * 256 + (s0 ^ ((d & 15) << 3))];
            *(bf16x8*)&VtOut[((size_t)((bb * 16 + hh) * 128 + d)) * 2048 + sbase + s0] = v;
        }
    }
}

// ---------------------------------------------------------------------------
// 128x256 counted-vmcnt GEMM for gemm_out.
// ---------------------------------------------------------------------------
__global__ __launch_bounds__(512) void gemm8n(const short* __restrict__ A,
                                              const short* __restrict__ BT,
                                              float* __restrict__ C,
                                              int N, int K, int nbx) {
    __shared__ short LA[2][2][4096];
    __shared__ short LBt[2][2][8192];

    const int tid = threadIdx.x, lane = tid & 63, w = tid >> 6;
    const int c16 = lane & 15, g = lane >> 4;
    const int wr = w >> 2, wc = w & 3;
    const int qph = (g ^ ((c16 >> 1) & 3)) * 8;

    const int nwg = gridDim.x;
    const int swz = (blockIdx.x & 7) * (nwg >> 3) + (blockIdx.x >> 3);
    const int brow = (swz / nbx) * 128, bcol = (swz % nbx) * 256;

    const int oA = tid * 16;
    const int rA = oA >> 6, lcA = ((oA >> 4) & 3) ^ ((rA >> 1) & 3);
    const short* aS = A + (size_t)(brow + rA) * K + lcA * 8;
    const int dA = oA >> 1;

    const int o0 = w * 1024 + lane * 16, o1 = o0 + 8192;
    const int r0 = o0 >> 6, lc0 = ((o0 >> 4) & 3) ^ ((r0 >> 1) & 3);
    const int r1 = o1 >> 6, lc1 = ((o1 >> 4) & 3) ^ ((r1 >> 1) & 3);
    const short* bS0 = BT + (size_t)(bcol + r0) * K + lc0 * 8;
    const short* bS1 = BT + (size_t)(bcol + r1) * K + lc1 * 8;
    const int d0 = o0 >> 1, d1 = o1 >> 1;

    f32x4 zero = {0.f, 0.f, 0.f, 0.f};
    f32x4 acc[4][4];
#pragma unroll
    for (int i = 0; i < 4; ++i)
#pragma unroll
        for (int j = 0; j < 4; ++j) acc[i][j] = zero;

    const int NT = K >> 6;
    async_ld16(aS,      &LA[0][0][dA]);
    async_ld16(aS + 32, &LA[0][1][dA]);
    async_ld16(bS0,      &LBt[0][0][d0]); async_ld16(bS1,      &LBt[0][0][d1]);
    async_ld16(bS0 + 32, &LBt[0][1][d0]); async_ld16(bS1 + 32, &LBt[0][1][d1]);
    asm volatile("s_waitcnt vmcnt(0)" ::: "memory");
    BARX();

    int cur = 0;
    const int arb = wr * 64, brb = wc * 64;
    for (int kt = 0; kt < NT; ++kt) {
        const bool stg = (kt + 1 < NT);
        const int ko = (kt + 1) * 64;
        bf16x8 af[4], bf[4];

#pragma unroll
        for (int mi = 0; mi < 4; ++mi)
            af[mi] = *(const bf16x8*)&LA[cur][0][(arb + mi * 16 + c16) * 32 + qph];
#pragma unroll
        for (int ni = 0; ni < 4; ++ni)
            bf[ni] = *(const bf16x8*)&LBt[cur][0][(brb + ni * 16 + c16) * 32 + qph];
        if (stg) {
            async_ld16(aS + ko, &LA[cur ^ 1][0][dA]);
            async_ld16(bS0 + ko, &LBt[cur ^ 1][0][d0]);
            async_ld16(bS1 + ko, &LBt[cur ^ 1][0][d1]);
            asm volatile("s_waitcnt vmcnt(3)" ::: "memory");
        } else {
            asm volatile("s_waitcnt vmcnt(0)" ::: "memory");
        }
        BARX();
        __builtin_amdgcn_s_setprio(1);
#pragma unroll
        for (int mi = 0; mi < 4; ++mi)
#pragma unroll
            for (int ni = 0; ni < 4; ++ni)
                acc[mi][ni] = __builtin_amdgcn_mfma_f32_16x16x32_bf16(af[mi], bf[ni], acc[mi][ni], 0, 0, 0);
        __builtin_amdgcn_s_setprio(0);
        BARX();

#pragma unroll
        for (int mi = 0; mi < 4; ++mi)
            af[mi] = *(const bf16x8*)&LA[cur][1][(arb + mi * 16 + c16) * 32 + qph];
#pragma unroll
        for (int ni = 0; ni < 4; ++ni)
            bf[ni] = *(const bf16x8*)&LBt[cur][1][(brb + ni * 16 + c16) * 32 + qph];
        if (stg) {
            async_ld16(aS + ko + 32, &LA[cur ^ 1][1][dA]);
            async_ld16(bS0 + ko + 32, &LBt[cur ^ 1][1][d0]);
            async_ld16(bS1 + ko + 32, &LBt[cur ^ 1][1][d1]);
            asm volatile("s_waitcnt vmcnt(3)" ::: "memory");
        }
        BARX();
        __builtin_amdgcn_s_setprio(1);
#pragma unroll
        for (int mi = 0; mi < 4; ++mi)
#pragma unroll
            for (int ni = 0; ni < 4; ++ni)
                acc[mi][ni] = __builtin_amdgcn_mfma_f32_16x16x32_bf16(af[mi], bf[ni], acc[mi][ni], 0, 0, 0);
        __builtin_amdgcn_s_setprio(0);
        BARX();

        cur ^= 1;
    }

#pragma unroll
    for (int mi = 0; mi < 4; ++mi)
#pragma unroll
        for (int ni = 0; ni < 4; ++ni)
#pragma unroll
            for (int reg = 0; reg < 4; ++reg) {
                int row = brow + wr * 64 + mi * 16 + 4 * g + reg;
                int col = bcol + wc * 64 + ni * 16 + c16;
                C[(size_t)row * N + col] = acc[mi][ni][reg];
            }
}

// ---------------------------------------------------------------------------
// LayerNorm(512) + RoPE(k_pe). ckv stride 640. Outputs bf16.
// ---------------------------------------------------------------------------
__global__ __launch_bounds__(256) void ln_rope(const float* __restrict__ ckv,
                                               const float* __restrict__ gam,
                                               const float* __restrict__ bet,
                                               const float* __restrict__ cosT,
                                               const float* __restrict__ sinT,
                                               const int* __restrict__ pid,
                                               short* __restrict__ kvcn,
                                               short* __restrict__ kpe) {
    const int tok = blockIdx.x, tid = threadIdx.x;
    const float* x = ckv + (size_t)tok * 640;
    float v0 = x[tid], v1 = x[tid + 256];
    float s = v0 + v1, sq = v0 * v0 + v1 * v1;
#pragma unroll
    for (int m = 1; m < 64; m <<= 1) { s += __shfl_xor(s, m); sq += __shfl_xor(sq, m); }
    __shared__ float ws[8];
    int wid = tid >> 6, lane = tid & 63;
    if (lane == 0) { ws[wid] = s; ws[4 + wid] = sq; }
    __syncthreads();
    s = ws[0] + ws[1] + ws[2] + ws[3];
    sq = ws[4] + ws[5] + ws[6] + ws[7];
    float mean = s * (1.f / 512.f);
    float var = sq * (1.f / 512.f) - mean * mean;
    float rstd = rsqrtf(var + EPS_);
    kvcn[(size_t)tok * 512 + tid]       = f2bf((v0 - mean) * rstd * gam[tid] + bet[tid]);
    kvcn[(size_t)tok * 512 + tid + 256] = f2bf((v1 - mean) * rstd * gam[tid + 256] + bet[tid + 256]);
    if (tid < 32) {
        int pos = pid[tok];
        float c = cosT[pos * 32 + tid], sn = sinT[pos * 32 + tid];
        float x1 = x[512 + tid], x2 = x[512 + 32 + tid];
        kpe[(size_t)tok * 64 + tid]      = f2bf(x1 * c - x2 * sn);
        kpe[(size_t)tok * 64 + 32 + tid] = f2bf(x2 * c + x1 * sn);
    }
}

// ---------------------------------------------------------------------------
// MFMA flash attention (R13: K+V LDS dbuf + complementary pairing + swapped
// QK^T softmax). Proven best; R14's single-buffer/3-block variant regressed
// (pairing > occupancy; second barrier per iter).
// ---------------------------------------------------------------------------
__global__ __launch_bounds__(256) void flash_mfma(const short* __restrict__ qb,
                                                  const short* __restrict__ kvb,
                                                  const short* __restrict__ kpe,
                                                  const short* __restrict__ Vt,
                                                  short* __restrict__ attno) {
    __shared__ short Ks[2][64 * 128];
    __shared__ short Vs[2][128 * 64];
    __shared__ short P[4][16][72];

    const int flat = blockIdx.x;              // 0..511
    const int xcd = flat & 7, idx = flat >> 3;
    const int bh = xcd + 8 * (idx >> 4);
    const int pair = idx & 15;
    const int b = bh >> 4, h = bh & 15;

    const int tid = threadIdx.x, lane = tid & 63, w = tid >> 6;
    const int c16 = lane & 15, g = lane >> 4, g8 = g * 8;
    const float SC2 = 0.10412063f;   // 1/sqrt(192) * log2(e)

    const int o = w * 1024 + lane * 16;
    const int rK = o >> 8, ccK = ((o >> 4) & 15) ^ (rK & 7);
    const int rV = o >> 7, ccV = ((o >> 4) & 7) ^ (rV & 7);
    const short* kB0  = kvb + ((size_t)((b * 2048 + rK) * 16 + h)) * 256 + ccK * 8;
    const short* vB0  = Vt + ((size_t)((b * 16 + h) * 128 + rV)) * 2048 + ccV * 8;
    const short* peB0 = kpe + (size_t)(b * 2048 + c16) * 64 + g8;

    f32x4 zero = {0.f, 0.f, 0.f, 0.f};

#define STAGE(BUF)                                                                  \
    {                                                                               \
        _Pragma("unroll")                                                           \
        for (int rnd = 0; rnd < 4; ++rnd)                                           \
            async_ld16(kRun + (size_t)rnd * 65536,                                  \
                       &Ks[BUF][(rnd * 4096 + w * 1024) >> 1]);                     \
        _Pragma("unroll")                                                           \
        for (int rnd = 0; rnd < 4; ++rnd)                                           \
            async_ld16(vRun + (size_t)rnd * 65536,                                  \
                       &Vs[BUF][(rnd * 4096 + w * 1024) >> 1]);                     \
        kRun += 64 * 4096;                                                          \
        vRun += 64;                                                                 \
    }

    for (int half = 0; half < 2; ++half) {
        const int qt = half ? (31 - pair) : pair;
        const int q0 = qt * 64;
        const int qrow = q0 + w * 16;

        const size_t qbase = ((size_t)(b * 2048 + qrow + c16) * 16 + h) * 192 + g8;
        bf16x8 qf[6];
#pragma unroll
        for (int ks = 0; ks < 6; ++ks) qf[ks] = *(const bf16x8*)(qb + qbase + 32 * ks);

        f32x4 acc[8];
#pragma unroll
        for (int i = 0; i < 8; ++i) acc[i] = zero;
        float mreg = -INFINITY;   // running max for q-row c16 (lane-local)
        float lreg = 0.f;         // per-lane partial row sum (deferred reduce)

        const short* kRun = kB0;
        const short* vRun = vB0;
        const short* peRun = peB0;

        const int nt = qt + 1;
        STAGE(0);
        __syncthreads();
        int cur = 0;

        for (int kt = 0; kt < nt; ++kt) {
            if (kt + 1 < nt) STAGE(cur ^ 1);

            f32x4 sc[4];
#pragma unroll
            for (int i = 0; i < 4; ++i) sc[i] = zero;

            // QK^T swapped: A = K fragment, B = Q fragment -> S[kv][q=c16]
            __builtin_amdgcn_s_setprio(1);
#pragma unroll
            for (int ks = 0; ks < 4; ++ks)
#pragma unroll
                for (int nb = 0; nb < 4; ++nb) {
                    int row = nb * 16 + c16;
                    bf16x8 kf = *(const bf16x8*)&Ks[cur][row * 128 + (((g + 4 * ks) ^ (row & 7)) << 3)];
                    sc[nb] = __builtin_amdgcn_mfma_f32_16x16x32_bf16(kf, qf[ks], sc[nb], 0, 0, 0);
                }
#pragma unroll
            for (int ks = 0; ks < 2; ++ks)
#pragma unroll
                for (int nb = 0; nb < 4; ++nb) {
                    bf16x8 kf = *(const bf16x8*)(peRun + (size_t)nb * 16 * 64 + ks * 32);
                    sc[nb] = __builtin_amdgcn_mfma_f32_16x16x32_bf16(kf, qf[4 + ks], sc[nb], 0, 0, 0);
                }
            __builtin_amdgcn_s_setprio(0);
            peRun += 64 * 64;

            // causal mask (last tile): kv_rel = 16nb+4g+reg > w*16 + c16
            if (kt == nt - 1) {
#pragma unroll
                for (int nb = 0; nb < 4; ++nb)
#pragma unroll
                    for (int reg = 0; reg < 4; ++reg)
                        if (nb * 16 + 4 * g + reg > w * 16 + c16) sc[nb][reg] = -INFINITY;
            }

            // row max: local tree (16 values) + 2 shuffle rounds (xor16, xor32)
            float m01 = fmaxf(fmaxf(sc[0][0], sc[0][1]), fmaxf(sc[0][2], sc[0][3]));
            float m23 = fmaxf(fmaxf(sc[1][0], sc[1][1]), fmaxf(sc[1][2], sc[1][3]));
            float m45 = fmaxf(fmaxf(sc[2][0], sc[2][1]), fmaxf(sc[2][2], sc[2][3]));
            float m67 = fmaxf(fmaxf(sc[3][0], sc[3][1]), fmaxf(sc[3][2], sc[3][3]));
            float rmax = fmaxf(fmaxf(m01, m23), fmaxf(m45, m67));
            rmax = fmaxf(rmax, __shfl_xor(rmax, 16));
            rmax = fmaxf(rmax, __shfl_xor(rmax, 32));

            // defer-rescale (T13, THR=8 in log2 domain)
            if (__any(rmax * SC2 - mreg > 8.f)) {
                float mnew = fmaxf(mreg, rmax * SC2);
                float alpha = exp2f(mreg - mnew);
                mreg = mnew;
                lreg *= alpha;
                float ar[4];
#pragma unroll
                for (int reg = 0; reg < 4; ++reg) ar[reg] = __shfl(alpha, 4 * g + reg);
#pragma unroll
                for (int nb = 0; nb < 8; ++nb)
#pragma unroll
                    for (int reg = 0; reg < 4; ++reg) acc[nb][reg] *= ar[reg];
            }

            // p = 2^(s*SC2 - m); per-lane partial sum; write P[q=c16][kv]
#pragma unroll
            for (int nb = 0; nb < 4; ++nb) {
                float p0 = exp2f(fmaf(sc[nb][0], SC2, -mreg));
                float p1 = exp2f(fmaf(sc[nb][1], SC2, -mreg));
                float p2 = exp2f(fmaf(sc[nb][2], SC2, -mreg));
                float p3 = exp2f(fmaf(sc[nb][3], SC2, -mreg));
                lreg += (p0 + p1) + (p2 + p3);
                short* pr = &P[w][c16][nb * 16 + 4 * g];
                pr[0] = f2bf(p0); pr[1] = f2bf(p1); pr[2] = f2bf(p2); pr[3] = f2bf(p3);
            }

            // PV from LDS V
            __builtin_amdgcn_s_setprio(1);
#pragma unroll
            for (int ks = 0; ks < 2; ++ks) {
                bf16x8 pf = *(const bf16x8*)&P[w][c16][ks * 32 + g8];
#pragma unroll
                for (int nb = 0; nb < 8; ++nb) {
                    int row = nb * 16 + c16;
                    bf16x8 vf = *(const bf16x8*)&Vs[cur][row * 64 + (((g + 4 * ks) ^ (row & 7)) << 3)];
                    acc[nb] = __builtin_amdgcn_mfma_f32_16x16x32_bf16(pf, vf, acc[nb], 0, 0, 0);
                }
            }
            __builtin_amdgcn_s_setprio(0);

            __syncthreads();
            cur ^= 1;
        }

        // epilogue: finish deferred row-sum (2 rounds), transpose to PV domain
        lreg += __shfl_xor(lreg, 16);
        lreg += __shfl_xor(lreg, 32);
        float linv[4];
#pragma unroll
        for (int reg = 0; reg < 4; ++reg) linv[reg] = 1.f / __shfl(lreg, 4 * g + reg);
#pragma unroll
        for (int nb = 0; nb < 8; ++nb)
#pragma unroll
            for (int reg = 0; reg < 4; ++reg)
                attno[((size_t)(b * 2048 + qrow + 4 * g + reg) * 16 + h) * 128 + nb * 16 + c16] =
                    f2bf(acc[nb][reg] * linv[reg]);
    }
#undef STAGE
}

// ---------------------------------------------------------------------------
extern "C" void kernel_launch(void* const* d_in, const int* in_sizes, int n_in,
                              void* d_out, int out_size, void* d_ws, size_t ws_size,
                              hipStream_t stream) {
    const float* hidden = (const float*)d_in[0];
    const float* cosT   = (const float*)d_in[1];
    const float* sinT   = (const float*)d_in[2];
    const int*   pid    = (const int*)d_in[3];
    const float* Wq     = (const float*)d_in[4];
    const float* Wkv_a  = (const float*)d_in[5];
    const float* ln_g   = (const float*)d_in[6];
    const float* ln_b   = (const float*)d_in[7];
    const float* Wkv_b  = (const float*)d_in[8];
    const float* Wo     = (const float*)d_in[9];
    float* out = (float*)d_out;

    char* p = (char*)d_ws;
    short* hid_bf = (short*)p;               p += (size_t)NTOK * 2048 * 2;
    short* WqkaT  = (short*)p;               p += (size_t)3840 * 2048 * 2;
    short* WkbT   = (short*)p;               p += (size_t)4096 * 512 * 2;
    short* WoT    = (short*)p;               p += (size_t)2048 * 2048 * 2;
    char*  big    = p;                       p += (size_t)NTOK * 3072 * 4;
    short* qbuf   = (short*)p;               p += (size_t)NTOK * 3072 * 2;
    short* kvcn   = (short*)p;               p += (size_t)NTOK * 512 * 2;
    short* kpe    = (short*)p;               p += (size_t)NTOK * 64 * 2;
    short* kvb    = (short*)p;               p += (size_t)NTOK * 4096 * 2;

    float* ckv   = (float*)big;
    short* Vt    = (short*)(big + (size_t)NTOK * 640 * 4);
    short* attno = (short*)(big + (size_t)NTOK * 640 * 4 + (size_t)2 * 16 * 128 * 2048 * 2);

    prep<<<22016, 256, 0, stream>>>(hidden, hid_bf, Wq, Wkv_a, Wkv_b, Wo, WqkaT, WkbT, WoT);
    gemm8<1><<<240, 512, 0, stream>>>(hid_bf, WqkaT, qbuf, ckv, nullptr,
                                      cosT, sinT, pid, 3840, 2048, 15);
    ln_rope<<<NTOK, 256, 0, stream>>>(ckv, ln_g, ln_b, cosT, sinT, pid, kvcn, kpe);
    gemm8<0><<<256, 512, 0, stream>>>(kvcn, WkbT, kvb, nullptr, Vt,
                                      nullptr, nullptr, nullptr, 4096, 512, 16);
    flash_mfma<<<512, 256, 0, stream>>>(qbuf, kvb, kpe, Vt, attno);
    gemm8n<<<256, 512, 0, stream>>>(attno, WoT, out, 2048, 2048, 8);
}